// Round 1
// baseline (363.264 us; speedup 1.0000x reference)
//
#include <hip/hip_runtime.h>

// Problem constants (from reference)
#define R_MAX 32
#define S_MAX 2
#define C_Z   128
#define NTB   (2 * R_MAX + 2 + 1)          // 67
#define IN_DIM (2 * NTB + (2 * S_MAX + 2) + 1)  // 141

__device__ __forceinline__ int clampi(int x, int lo, int hi) {
    return min(max(x, lo), hi);
}

// One thread = one float4 chunk of one (i,j) pair's 128-ch output row.
// 32 lanes per pair -> fully coalesced 16B stores.
__global__ __launch_bounds__(256) void relpos_kernel(
    const int* __restrict__ asym_id,
    const int* __restrict__ entity_id,
    const int* __restrict__ residue_index,
    const int* __restrict__ token_index,
    const int* __restrict__ sym_id,
    const int* __restrict__ mask,       // (B,N,N) nonzero = true
    const float* __restrict__ W,        // (IN_DIM, C_Z) row-major
    float* __restrict__ out,            // (B,N,N,C_Z)
    int N, long long total_pairs)
{
    long long t = (long long)blockIdx.x * blockDim.x + threadIdx.x;
    int chunk = (int)(t & 31);          // which float4 of the 128 channels
    long long p = t >> 5;               // pair index: b*N*N + i*N + j
    if (p >= total_pairs) return;

    long long row_i = p / N;            // = b*N + i
    int j_local = (int)(p - row_i * (long long)N);
    long long b = row_i / N;
    long long row_j = b * (long long)N + j_local;

    int ai = asym_id[row_i],        aj = asym_id[row_j];
    int ei = entity_id[row_i],      ej = entity_id[row_j];
    int ri = residue_index[row_i],  rj = residue_index[row_j];
    int ti = token_index[row_i],    tj = token_index[row_j];
    int si = sym_id[row_i],         sj = sym_id[row_j];

    bool same_chain  = (ai == aj);
    bool same_entity = (ei == ej);
    bool same_res    = (ri == rj);

    int d_res   = same_chain ? clampi(ri - rj + R_MAX, 0, 2 * R_MAX) : (2 * R_MAX + 1);
    int d_tok   = (same_chain && same_res) ? clampi(ti - tj + R_MAX, 0, 2 * R_MAX)
                                           : (2 * R_MAX + 1);
    int d_chain = same_entity ? clampi(si - sj + S_MAX, 0, 2 * S_MAX) : (2 * S_MAX + 1);

    if (mask[p] != 0) { d_tok = NTB - 1; d_res = NTB - 1; }

    const float4* Wr = (const float4*)(W + (size_t)d_res * C_Z);
    const float4* Wt = (const float4*)(W + (size_t)(NTB + d_tok) * C_Z);
    const float4* We = (const float4*)(W + (size_t)(2 * NTB) * C_Z);
    const float4* Wc = (const float4*)(W + (size_t)(2 * NTB + 1 + d_chain) * C_Z);

    float4 r  = Wr[chunk];
    float4 tk = Wt[chunk];
    float4 e  = We[chunk];
    float4 c  = Wc[chunk];

    float se = same_entity ? 1.0f : 0.0f;
    float4 o;
    o.x = r.x + tk.x + se * e.x + c.x;
    o.y = r.y + tk.y + se * e.y + c.y;
    o.z = r.z + tk.z + se * e.z + c.z;
    o.w = r.w + tk.w + se * e.w + c.w;

    ((float4*)out)[p * 32 + chunk] = o;
}

extern "C" void kernel_launch(void* const* d_in, const int* in_sizes, int n_in,
                              void* d_out, int out_size, void* d_ws, size_t ws_size,
                              hipStream_t stream) {
    const int*   asym_id       = (const int*)d_in[0];
    const int*   entity_id     = (const int*)d_in[1];
    const int*   residue_index = (const int*)d_in[2];
    const int*   token_index   = (const int*)d_in[3];
    const int*   sym_id        = (const int*)d_in[4];
    const int*   mask          = (const int*)d_in[5];
    const float* W             = (const float*)d_in[6];
    float*       out           = (float*)d_out;

    long long BN      = in_sizes[0];              // B*N
    long long mask_sz = in_sizes[5];              // B*N*N
    int N = (int)(mask_sz / BN);
    long long total_pairs = mask_sz;              // B*N*N
    long long total_threads = total_pairs * 32;   // one float4 per thread

    const int block = 256;
    unsigned grid = (unsigned)((total_threads + block - 1) / block);

    relpos_kernel<<<grid, block, 0, stream>>>(
        asym_id, entity_id, residue_index, token_index, sym_id,
        mask, W, out, N, total_pairs);
}

// Round 2
// 361.441 us; speedup vs baseline: 1.0050x; 1.0050x over previous
//
#include <hip/hip_runtime.h>

// Problem constants (from reference)
#define R_MAX 32
#define S_MAX 2
#define C_Z   128
#define NTB   (2 * R_MAX + 2 + 1)               // 67
#define IN_DIM (2 * NTB + (2 * S_MAX + 2) + 1)  // 141
#define JT   256                                 // j-tile width per block

__device__ __forceinline__ int clampi(int x, int lo, int hi) {
    return min(max(x, lo), hi);
}

// Grid: (ceil(N/JT), B*N). Block: 256 threads.
// Phase 1: 256 threads compute packed bin codes for the 256 j's of this tile.
// Phase 2: 32 iterations x (8 pairs x 32 chunk-lanes) of gather+add+store.
__global__ __launch_bounds__(256) void relpos_kernel(
    const int* __restrict__ asym_id,        // (B*N)
    const int* __restrict__ entity_id,
    const int* __restrict__ residue_index,
    const int* __restrict__ token_index,
    const int* __restrict__ sym_id,
    const int* __restrict__ mask,           // (B*N*N)
    const float* __restrict__ W,            // (IN_DIM, C_Z)
    float* __restrict__ out,                // (B*N*N, C_Z)
    int N)
{
    __shared__ int code_s[JT];

    const int tid = threadIdx.x;
    const int row = blockIdx.y;             // b*N + i  (flat row over B,N)
    const int jb  = blockIdx.x * JT;
    const int b   = row / N;                // uniform scalar div, once per block

    // i-side scalars: wave-uniform loads
    const int ai = asym_id[row];
    const int ei = entity_id[row];
    const int ri = residue_index[row];
    const int ti = token_index[row];
    const int si = sym_id[row];

    // ---- Phase 1: bins for this j-tile, packed into LDS ----
    {
        int j = jb + tid;
        int code = 0;
        if (j < N) {
            int jrow = b * N + j;
            int aj = asym_id[jrow];
            int ej = entity_id[jrow];
            int rj = residue_index[jrow];
            int tj = token_index[jrow];
            int sj = sym_id[jrow];

            bool same_chain  = (ai == aj);
            bool same_entity = (ei == ej);
            bool same_res    = (ri == rj);

            int d_res   = same_chain ? clampi(ri - rj + R_MAX, 0, 2 * R_MAX) : (2 * R_MAX + 1);
            int d_tok   = (same_chain && same_res) ? clampi(ti - tj + R_MAX, 0, 2 * R_MAX)
                                                   : (2 * R_MAX + 1);
            int d_chain = same_entity ? clampi(si - sj + S_MAX, 0, 2 * S_MAX) : (2 * S_MAX + 1);

            if (mask[(long long)row * N + j] != 0) { d_res = NTB - 1; d_tok = NTB - 1; }

            code = d_res | (d_tok << 7) | (d_chain << 14) | (same_entity ? (1 << 17) : 0);
        }
        code_s[tid] = code;
    }
    __syncthreads();

    // ---- Phase 2: stream the output tile ----
    const int chunk = tid & 31;             // which float4 of 128 channels
    const int psub  = tid >> 5;             // 0..7: pair-slot within iteration
    const float4* __restrict__ W4 = (const float4*)W;

    // w_ent row: fixed per lane -> registers
    const float4 e = W4[(2 * NTB) * 32 + chunk];

    float4* __restrict__ outp = (float4*)out + ((long long)row * N + jb) * 32;
    const int jmax = min(JT, N - jb);       // pairs in this tile

    #pragma unroll 4
    for (int it = 0; it < JT / 8; ++it) {
        int pair = it * 8 + psub;
        if (pair >= jmax) break;
        int code = code_s[pair];            // LDS broadcast within 32 lanes

        int d_res   = code & 127;
        int d_tok   = (code >> 7) & 127;
        int d_chain = (code >> 14) & 7;
        float se    = (code >> 17) ? 1.0f : 0.0f;

        float4 r = W4[d_res * 32 + chunk];
        float4 t = W4[(NTB + d_tok) * 32 + chunk];
        float4 c = W4[(2 * NTB + 1 + d_chain) * 32 + chunk];

        float4 o;
        o.x = r.x + t.x + se * e.x + c.x;
        o.y = r.y + t.y + se * e.y + c.y;
        o.z = r.z + t.z + se * e.z + c.z;
        o.w = r.w + t.w + se * e.w + c.w;

        outp[(long long)pair * 32 + chunk] = o;
    }
}

extern "C" void kernel_launch(void* const* d_in, const int* in_sizes, int n_in,
                              void* d_out, int out_size, void* d_ws, size_t ws_size,
                              hipStream_t stream) {
    const int*   asym_id       = (const int*)d_in[0];
    const int*   entity_id     = (const int*)d_in[1];
    const int*   residue_index = (const int*)d_in[2];
    const int*   token_index   = (const int*)d_in[3];
    const int*   sym_id        = (const int*)d_in[4];
    const int*   mask          = (const int*)d_in[5];
    const float* W             = (const float*)d_in[6];
    float*       out           = (float*)d_out;

    long long BN      = in_sizes[0];        // B*N
    long long mask_sz = in_sizes[5];        // B*N*N
    int N = (int)(mask_sz / BN);

    dim3 grid((unsigned)((N + JT - 1) / JT), (unsigned)BN);
    dim3 block(256);

    relpos_kernel<<<grid, block, 0, stream>>>(
        asym_id, entity_id, residue_index, token_index, sym_id,
        mask, W, out, N);
}

// Round 4
// 319.804 us; speedup vs baseline: 1.1359x; 1.1302x over previous
//
#include <hip/hip_runtime.h>

// Problem constants (from reference)
#define R_MAX 32
#define S_MAX 2
#define C_Z   128
#define NTB   (2 * R_MAX + 2 + 1)               // 67
#define IN_DIM (2 * NTB + (2 * S_MAX + 2) + 1)  // 141
#define JT   256                                 // j-tile width per block

typedef float vf4 __attribute__((ext_vector_type(4)));  // native vec4 for nontemporal store

__device__ __forceinline__ int clampi(int x, int lo, int hi) {
    return min(max(x, lo), hi);
}

// Grid: (ceil(N/JT), B*N). Block: 256 threads.
// Phase 1: 256 threads compute packed bin codes for the 256 j's of this tile,
//          stored TRANSPOSED in LDS so phase 2 can bulk-load them.
// Phase 2: each thread preloads its 32 codes into registers (8x ds_read_b128
//          broadcasts), then runs a fully-unrolled pure stream:
//          3 L1 gathers + fma-add + nontemporal float4 store per pair.
__global__ __launch_bounds__(256) void relpos_kernel(
    const int* __restrict__ asym_id,        // (B*N)
    const int* __restrict__ entity_id,
    const int* __restrict__ residue_index,
    const int* __restrict__ token_index,
    const int* __restrict__ sym_id,
    const int* __restrict__ mask,           // (B*N*N)
    const float* __restrict__ W,            // (IN_DIM, C_Z)
    float* __restrict__ out,                // (B*N*N, C_Z)
    int N)
{
    __shared__ int codeT[JT];               // transposed: codeT[(j&7)*32 + (j>>3)]

    const int tid = threadIdx.x;
    const int row = blockIdx.y;             // b*N + i
    const int jb  = blockIdx.x * JT;
    const int b   = row / N;

    // i-side scalars (wave-uniform)
    const int ai = asym_id[row];
    const int ei = entity_id[row];
    const int ri = residue_index[row];
    const int ti = token_index[row];
    const int si = sym_id[row];

    // ---- Phase 1: bins for this j-tile ----
    {
        int j = jb + tid;
        int code = 0;
        if (j < N) {
            int jrow = b * N + j;
            int aj = asym_id[jrow];
            int ej = entity_id[jrow];
            int rj = residue_index[jrow];
            int tj = token_index[jrow];
            int sj = sym_id[jrow];

            bool same_chain  = (ai == aj);
            bool same_entity = (ei == ej);
            bool same_res    = (ri == rj);

            int d_res   = same_chain ? clampi(ri - rj + R_MAX, 0, 2 * R_MAX) : (2 * R_MAX + 1);
            int d_tok   = (same_chain && same_res) ? clampi(ti - tj + R_MAX, 0, 2 * R_MAX)
                                                   : (2 * R_MAX + 1);
            int d_chain = same_entity ? clampi(si - sj + S_MAX, 0, 2 * S_MAX) : (2 * S_MAX + 1);

            if (mask[(long long)row * N + j] != 0) { d_res = NTB - 1; d_tok = NTB - 1; }

            code = d_res | (d_tok << 7) | (d_chain << 14) | (same_entity ? (1 << 17) : 0);
        }
        codeT[(tid & 7) * 32 + (tid >> 3)] = code;   // transposed store
    }
    __syncthreads();

    // ---- Phase 2: pure output stream ----
    const int chunk = tid & 31;             // which float4 of 128 channels
    const int psub  = tid >> 5;             // 0..7: pair-slot
    const vf4* __restrict__ W4 = (const vf4*)W + chunk;  // chunk-offset base

    // w_ent row chunk: loop-invariant
    const vf4 e = W4[(2 * NTB) * 32];

    vf4* __restrict__ outp = (vf4*)out + ((long long)row * N + jb) * 32 + chunk;
    const int jmax = min(JT, N - jb);

    // Preload this thread's 32 codes: codeT[psub*32 + it], it = 0..31
    int4 creg[8];
    {
        const int4* cp = (const int4*)&codeT[psub * 32];
        #pragma unroll
        for (int k = 0; k < 8; ++k) creg[k] = cp[k];   // ds_read_b128, broadcast
    }

#define PROC(codev, itv)                                                      \
    {                                                                         \
        int code    = (codev);                                                \
        int pair    = (itv) * 8 + psub;                                       \
        int d_res   = code & 127;                                             \
        int d_tok   = (code >> 7) & 127;                                      \
        int d_chain = (code >> 14) & 7;                                       \
        float se    = (float)((code >> 17) & 1);                              \
        vf4 r  = W4[d_res * 32];                                              \
        vf4 t  = W4[(NTB + d_tok) * 32];                                      \
        vf4 cc = W4[(2 * NTB + 1 + d_chain) * 32];                            \
        vf4 o  = r + t + se * e + cc;                                         \
        __builtin_nontemporal_store(o, &outp[pair * 32]);                     \
    }

    if (jmax == JT) {
        // fast path: no bounds checks, 4 independent bodies per unroll step
        #pragma unroll
        for (int k = 0; k < 8; ++k) {
            int4 c = creg[k];
            PROC(c.x, 4 * k + 0)
            PROC(c.y, 4 * k + 1)
            PROC(c.z, 4 * k + 2)
            PROC(c.w, 4 * k + 3)
        }
    } else {
        #pragma unroll
        for (int k = 0; k < 8; ++k) {
            int4 c = creg[k];
            if (4 * k * 8 + psub < jmax)       PROC(c.x, 4 * k + 0)
            if ((4 * k + 1) * 8 + psub < jmax) PROC(c.y, 4 * k + 1)
            if ((4 * k + 2) * 8 + psub < jmax) PROC(c.z, 4 * k + 2)
            if ((4 * k + 3) * 8 + psub < jmax) PROC(c.w, 4 * k + 3)
        }
    }
#undef PROC
}

extern "C" void kernel_launch(void* const* d_in, const int* in_sizes, int n_in,
                              void* d_out, int out_size, void* d_ws, size_t ws_size,
                              hipStream_t stream) {
    const int*   asym_id       = (const int*)d_in[0];
    const int*   entity_id     = (const int*)d_in[1];
    const int*   residue_index = (const int*)d_in[2];
    const int*   token_index   = (const int*)d_in[3];
    const int*   sym_id        = (const int*)d_in[4];
    const int*   mask          = (const int*)d_in[5];
    const float* W             = (const float*)d_in[6];
    float*       out           = (float*)d_out;

    long long BN      = in_sizes[0];        // B*N
    long long mask_sz = in_sizes[5];        // B*N*N
    int N = (int)(mask_sz / BN);

    dim3 grid((unsigned)((N + JT - 1) / JT), (unsigned)BN);
    dim3 block(256);

    relpos_kernel<<<grid, block, 0, stream>>>(
        asym_id, entity_id, residue_index, token_index, sym_id,
        mask, W, out, N);
}